// Round 12
// baseline (68.328 us; speedup 1.0000x reference)
//
#include <hip/hip_runtime.h>

#define BATCH 512
#define TT    1024
#define NST   64
#define NSYM  32
#define NCH   64      // chunks per chain (4 waves x 16 MFMA columns)
#define CLEN  16      // TT / NCH
#define WARM  16      // warmup steps
#define LN2F  0.69314718055994530942f

#define AP_MV    6400   // dword offset: packed matvec A-frags  [4mt][2kc][64][4]
#define AP_EM    8448   // dword offset: packed emission A-frags [4mt][64][4]
#define WS_STATS 9472   // float offset: per-(chain,chunk) Lstart  [512][64]

typedef _Float16 f16x8 __attribute__((ext_vector_type(8)));
typedef float    f32x4 __attribute__((ext_vector_type(4)));

#define MFMA_F16(a,b,c) __builtin_amdgcn_mfma_f32_16x16x32_f16(a,b,c,0,0,0)

// cvt_pkrtz returns __fp16 ext_vector(2); bit-cast through unsigned (same size).
__device__ __forceinline__ unsigned pkrtz_u(float a, float b) {
    return __builtin_bit_cast(unsigned, __builtin_amdgcn_cvt_pkrtz(a, b));
}

// slot(g, r) -> k within a K=32 chunk.  Chosen to match the D-layout
// (row = 4g + reg), so D of step t IS the B-operand of step t+1 per-lane.
// Correct for ANY true hw map as long as A and B share it (k-sum is
// permutation-invariant; A is packed with this same sigma in prep).
__device__ __forceinline__ int sigma_k(int g, int r) {
    return (r < 4) ? (4 * g + r) : (16 + 4 * g + (r - 4));
}

__device__ __forceinline__ f16x8 pk8(float a0, float a1, float a2, float a3,
                                     float a4, float a5, float a6, float a7) {
    union U { unsigned u[4]; f16x8 v; } u;
    u.u[0] = pkrtz_u(a0, a1);
    u.u[1] = pkrtz_u(a2, a3);
    u.u[2] = pkrtz_u(a4, a5);
    u.u[3] = pkrtz_u(a6, a7);
    return u.v;
}

// ---------------------------------------------------------------------------
// Prep.  Phase 1: softmaxes -> ws[0..6207] (A rows, B rows, I).
// Phase 2 (after barrier): pack A^T and Bem into f16 MFMA fragments using
// sigma_k, so the scan loads operand registers directly.
// ---------------------------------------------------------------------------
__global__ __launch_bounds__(64) void hmm_prep(
    const float* __restrict__ em, const float* __restrict__ tr,
    const float* __restrict__ ini, float* __restrict__ ws)
{
    const int n = threadIdx.x;

    {
        float a[64];
        float m = -1e30f;
        #pragma unroll
        for (int j = 0; j < 64; ++j) { a[j] = tr[n * 64 + j]; m = fmaxf(m, a[j]); }
        float s = 0.f;
        #pragma unroll
        for (int j = 0; j < 64; ++j) { a[j] = __expf(a[j] - m); s += a[j]; }
        const float inv = 1.f / s;
        #pragma unroll
        for (int j = 0; j < 64; ++j) ws[n * 64 + j] = a[j] * inv;
    }
    {
        float bv[32];
        float m = -1e30f;
        #pragma unroll
        for (int j = 0; j < 32; ++j) { bv[j] = em[n * 32 + j]; m = fmaxf(m, bv[j]); }
        float s = 0.f;
        #pragma unroll
        for (int j = 0; j < 32; ++j) { bv[j] = __expf(bv[j] - m); s += bv[j]; }
        const float inv = 1.f / s;
        #pragma unroll
        for (int j = 0; j < 32; ++j) ws[4096 + n * 32 + j] = bv[j] * inv;
    }
    {
        float v = ini[n];
        float m = v;
        #pragma unroll
        for (int off = 32; off; off >>= 1) m = fmaxf(m, __shfl_xor(m, off, 64));
        const float e = __expf(v - m);
        float s = e;
        #pragma unroll
        for (int off = 32; off; off >>= 1) s += __shfl_xor(s, off, 64);
        ws[6144 + n] = e / s;
    }

    __syncthreads();   // global writes visible within the block

    // Phase 2: fragment packing (thread n = lane n of the future scan wave)
    const int g   = n >> 4;
    const int cl  = n & 15;
    unsigned* wsu = (unsigned*)ws;

    #pragma unroll
    for (int mt = 0; mt < 4; ++mt) {
        // matvec A-op: A_op[m][k] = Asm[k][m]  (mv = A^T h)
        #pragma unroll
        for (int kc = 0; kc < 2; ++kc) {
            #pragma unroll
            for (int p = 0; p < 4; ++p) {
                const int k0 = sigma_k(g, 2 * p);
                const int k1 = sigma_k(g, 2 * p + 1);
                const int m  = 16 * mt + cl;
                const float a0 = ws[(32 * kc + k0) * 64 + m];
                const float a1 = ws[(32 * kc + k1) * 64 + m];
                wsu[AP_MV + ((mt * 2 + kc) * 64 + n) * 4 + p] = pkrtz_u(a0, a1);
            }
        }
        // emission A-op: A_op[state][sym] = Bsm[state][sym]
        #pragma unroll
        for (int p = 0; p < 4; ++p) {
            const int k0 = sigma_k(g, 2 * p);
            const int k1 = sigma_k(g, 2 * p + 1);
            const int st = 16 * mt + cl;
            const float b0 = ws[4096 + st * 32 + k0];
            const float b1 = ws[4096 + st * 32 + k1];
            wsu[AP_EM + (mt * 64 + n) * 4 + p] = pkrtz_u(b0, b1);
        }
    }
}

// ---------------------------------------------------------------------------
// MFMA scan: 4 waves per chain; wave w owns chunks 16w..16w+15 (MFMA cols).
//  Per step (advances 16 chunks one t):
//   E  = Bem(64x32) @ x(32x16)      4 MFMAs
//   mv = A^T(64x64) @ h(64x16)      8 MFMAs  (B operand = repacked D, no xlane)
//   h  = (E * sc) o mv              sc = exact power of 2, readlane proxy col15
//  Delayed outputs (f via float4 stores, local ll); Lstart saved per chunk;
//  hmm_fix telescopes ll across chunks.  16-step warmup from h=1 (proven R9);
//  chunk 0 gets an exact E0 o I restart.
// ---------------------------------------------------------------------------
__global__ __launch_bounds__(64, 1) void hmm_scan(
    const float* __restrict__ inputs, float* __restrict__ ws,
    float* __restrict__ out)
{
    const int lane = threadIdx.x;
    const int col  = lane & 15;          // MFMA column
    const int g    = lane >> 4;
    const int b    = blockIdx.x >> 2;    // chain
    const int w    = blockIdx.x & 3;     // wave-slot -> chunk group
    const int c    = 16 * w + col;       // this column's chunk
    const int t0   = c * CLEN;
    const bool isc0 = (c == 0);

    // operand fragments (invariant)
    f16x8 Amv[4][2], Aem[4];
    {
        const int4* mvp = (const int4*)((const unsigned*)ws + AP_MV);
        #pragma unroll
        for (int mt = 0; mt < 4; ++mt)
            #pragma unroll
            for (int kc = 0; kc < 2; ++kc)
                Amv[mt][kc] = __builtin_bit_cast(f16x8, mvp[(mt * 2 + kc) * 64 + lane]);
        const int4* emp = (const int4*)((const unsigned*)ws + AP_EM);
        #pragma unroll
        for (int mt = 0; mt < 4; ++mt)
            Aem[mt] = __builtin_bit_cast(f16x8, emp[mt * 64 + lane]);
    }

    const float* __restrict__ xp = inputs + (size_t)b * (TT * NSYM);
    float* __restrict__ op       = out    + (size_t)b * (TT * 65);

    // x prefetch ring, depth 4 (per lane: its column's row, two float4 halves)
    float4 rga[4], rgb[4];
    auto loadx = [&](int k, int s) {
        int t = t0 + k;
        t = t < 0 ? 0 : t;
        t = t > TT - 1 ? TT - 1 : t;
        const float* row = xp + (size_t)t * NSYM;
        rga[s] = *(const float4*)(row + 4 * g);
        rgb[s] = *(const float4*)(row + 16 + 4 * g);
    };

    // h in D layout: hD[mt][r] = h[state = 16*mt + 4*g + r][chunk col]
    float hD[4][4];
    #pragma unroll
    for (int mt = 0; mt < 4; ++mt)
        #pragma unroll
        for (int r = 0; r < 4; ++r) hD[mt][r] = 1.0f;
    int Esum = 0;

    const f32x4 z4 = {0.f, 0.f, 0.f, 0.f};

    auto step = [&](int k, int s, bool store_) {
        // ---- delayed outputs for row t-1 (uses hD = h_{t-1}, pre-update Esum)
        if (store_) {
            float p = 0.f;
            #pragma unroll
            for (int mt = 0; mt < 4; ++mt)
                #pragma unroll
                for (int r = 0; r < 4; ++r) p += hD[mt][r];
            p += __shfl_xor(p, 16, 64);
            p += __shfl_xor(p, 32, 64);          // column total in all 4 g-lanes
            const float rS = __builtin_amdgcn_rcpf(p);
            float* rowp = op + (size_t)(t0 + k - 1) * 65;
            #pragma unroll
            for (int mt = 0; mt < 4; ++mt) {
                const float4 v4 = {hD[mt][0] * rS, hD[mt][1] * rS,
                                   hD[mt][2] * rS, hD[mt][3] * rS};
                *(float4*)(rowp + 16 * mt + 4 * g) = v4;
            }
            if (g == 0) rowp[64] = __logf(p) + (float)Esum * LN2F;
        }
        // ---- power-of-2 rescale; proxy = state 0 of col 15 (never reset)
        const int pb = __builtin_amdgcn_readlane(__float_as_int(hD[0][0]), 15);
        int ex = (pb >> 23) & 255;
        ex = ex < 1 ? 1 : (ex > 253 ? 253 : ex);
        const float sc = __uint_as_float((unsigned)(254 - ex) << 23);  // 2^(127-ex)
        Esum += ex - 127;
        // ---- emission MFMA
        const f16x8 bx = pk8(rga[s].x, rga[s].y, rga[s].z, rga[s].w,
                             rgb[s].x, rgb[s].y, rgb[s].z, rgb[s].w);
        f32x4 E[4];
        #pragma unroll
        for (int mt = 0; mt < 4; ++mt) E[mt] = MFMA_F16(Aem[mt], bx, z4);
        // ---- matvec MFMA (B operand = repacked hD, zero cross-lane)
        const f16x8 bh0 = pk8(hD[0][0], hD[0][1], hD[0][2], hD[0][3],
                              hD[1][0], hD[1][1], hD[1][2], hD[1][3]);
        const f16x8 bh1 = pk8(hD[2][0], hD[2][1], hD[2][2], hD[2][3],
                              hD[3][0], hD[3][1], hD[3][2], hD[3][3]);
        f32x4 mv[4];
        #pragma unroll
        for (int mt = 0; mt < 4; ++mt) {
            mv[mt] = MFMA_F16(Amv[mt][0], bh0, z4);
            mv[mt] = MFMA_F16(Amv[mt][1], bh1, mv[mt]);
        }
        // ---- h update
        #pragma unroll
        for (int mt = 0; mt < 4; ++mt)
            #pragma unroll
            for (int r = 0; r < 4; ++r)
                hD[mt][r] = (E[mt][r] * sc) * mv[mt][r];
        // ---- refill ring
        loadx(k + 4, s);
    };

    // prologue: ring k = -16..-13
    #pragma unroll
    for (int s = 0; s < 4; ++s) loadx(-WARM + s, s);

    // warmup k = -16..-1 (no outputs; chunk 0 clamps to row 0 = garbage chain)
    for (int kk = -WARM; kk < 0; kk += 4) {
        #pragma unroll
        for (int s = 0; s < 4; ++s) step(kk + s, s, false);
    }

    // Lstart (state at t0-1), before the silent step
    float Lstart;
    {
        float p = 0.f;
        #pragma unroll
        for (int mt = 0; mt < 4; ++mt)
            #pragma unroll
            for (int r = 0; r < 4; ++r) p += hD[mt][r];
        p += __shfl_xor(p, 16, 64);
        p += __shfl_xor(p, 32, 64);
        Lstart = __logf(p) + (float)Esum * LN2F;
    }
    Lstart = isc0 ? 0.f : Lstart;

    // k = 0: silent step (consumes row t0; row t0-1 belongs to chunk c-1)
    step(0, 0, false);

    // chunk-0 exact restart: h_0 = E_0 o I
    {
        const float* row = xp;               // chunk 0 -> row 0
        const float4 xa = *(const float4*)(row + 4 * g);
        const float4 xb = *(const float4*)(row + 16 + 4 * g);
        const f16x8 bx0 = pk8(xa.x, xa.y, xa.z, xa.w, xb.x, xb.y, xb.z, xb.w);
        #pragma unroll
        for (int mt = 0; mt < 4; ++mt) {
            const f32x4 E0 = MFMA_F16(Aem[mt], bx0, z4);
            const float4 iv = *(const float4*)(ws + 6144 + 16 * mt + 4 * g);
            const float ivv[4] = {iv.x, iv.y, iv.z, iv.w};
            #pragma unroll
            for (int r = 0; r < 4; ++r)
                if (isc0) hD[mt][r] = E0[r] * ivv[r];
        }
        if (isc0) Esum = 0;
    }

    // main: k = 1..15, outputs for rows t0..t0+14
    #pragma unroll
    for (int s = 1; s < 4; ++s) step(s, s, true);
    #pragma unroll
    for (int kk = 4; kk <= 12; kk += 4) {
        #pragma unroll
        for (int s = 0; s < 4; ++s) step(kk + s, s, true);
    }

    // epilogue: row t0+15 (local ll = Lend) + Lstart stat
    {
        float p = 0.f;
        #pragma unroll
        for (int mt = 0; mt < 4; ++mt)
            #pragma unroll
            for (int r = 0; r < 4; ++r) p += hD[mt][r];
        p += __shfl_xor(p, 16, 64);
        p += __shfl_xor(p, 32, 64);
        const float rS = __builtin_amdgcn_rcpf(p);
        float* rowp = op + (size_t)(t0 + CLEN - 1) * 65;
        #pragma unroll
        for (int mt = 0; mt < 4; ++mt) {
            const float4 v4 = {hD[mt][0] * rS, hD[mt][1] * rS,
                               hD[mt][2] * rS, hD[mt][3] * rS};
            *(float4*)(rowp + 16 * mt + 4 * g) = v4;
        }
        if (g == 0) {
            rowp[64] = __logf(p) + (float)Esum * LN2F;   // local Lend
            ws[WS_STATS + (size_t)b * NCH + c] = Lstart;
        }
    }
}

// ---------------------------------------------------------------------------
// Fixup: per chain, D_c = Lend_c(local, read from out) - Lstart_c; exclusive
// prefix O_c; then ll[t] += O_{t/16} - Lstart_{t/16}.  Chunk 0: O=0, Ls=0.
// ---------------------------------------------------------------------------
__global__ __launch_bounds__(64) void hmm_fix(
    const float* __restrict__ ws, float* __restrict__ out)
{
    const int b    = blockIdx.x;
    const int lane = threadIdx.x;   // = chunk index c

    float* __restrict__ op = out + (size_t)b * (TT * 65);

    const float Ls = ws[WS_STATS + (size_t)b * NCH + lane];
    const float Le = op[(size_t)(lane * CLEN + CLEN - 1) * 65 + 64];
    const float D  = Le - Ls;

    float O = 0.f;
    #pragma unroll
    for (int j = 0; j < NCH - 1; ++j) {
        const float Dj = __int_as_float(
            __builtin_amdgcn_readlane(__float_as_int(D), j));
        if (lane > j) O += Dj;
    }
    const float offs = O - Ls;

    #pragma unroll
    for (int k = 0; k < 16; ++k) {
        const int row  = k * 64 + lane;
        const int cidx = row >> 4;                     // row / CLEN
        const float offk = __shfl(offs, cidx, 64);
        op[(size_t)row * 65 + 64] += offk;
    }
}

// ---------------------------------------------------------------------------
extern "C" void kernel_launch(void* const* d_in, const int* in_sizes, int n_in,
                              void* d_out, int out_size, void* d_ws, size_t ws_size,
                              hipStream_t stream) {
    const float* inputs = (const float*)d_in[0];  // [512,1024,32]
    const float* em     = (const float*)d_in[1];  // [64,32]
    const float* tr     = (const float*)d_in[2];  // [64,64]
    const float* ini    = (const float*)d_in[3];  // [64]
    float* out = (float*)d_out;                   // [512,1024,65]
    float* ws  = (float*)d_ws;                    // ~42240 floats used (~169 KB)

    hmm_prep<<<1, 64, 0, stream>>>(em, tr, ini, ws);
    hmm_scan<<<BATCH * 4, 64, 0, stream>>>(inputs, ws, out);
    hmm_fix<<<BATCH, 64, 0, stream>>>(ws, out);
}